// Round 4
// baseline (646.536 us; speedup 1.0000x reference)
//
#include <hip/hip_runtime.h>
#include <hip/hip_bf16.h>

#define S 4096
#define D 2048
#define NH 16
#define HD 128

typedef __attribute__((ext_vector_type(8))) short bf16x8;
typedef __attribute__((ext_vector_type(4))) float f32x4;

typedef __attribute__((address_space(1))) char glob_char;
typedef __attribute__((address_space(3))) char lds_char_t;

__device__ __forceinline__ void gld16(const void* g, void* l) {
    __builtin_amdgcn_global_load_lds((const glob_char*)g, (lds_char_t*)l, 16, 0, 0);
}

__device__ __forceinline__ unsigned short f2b(float f) {
    union { float f; unsigned u; } c; c.f = f;
    unsigned r = c.u + 0x7fff + ((c.u >> 16) & 1);
    return (unsigned short)(r >> 16);
}
__device__ __forceinline__ float b2f(unsigned short u) {
    union { unsigned u; float f; } c; c.u = ((unsigned)u) << 16;
    return c.f;
}

// ---------------- fp32 -> bf16 conversion (all 5 tensors, one launch) ----
__global__ __launch_bounds__(256) void cvt_all(
    const float* __restrict__ x,  const float* __restrict__ wq,
    const float* __restrict__ wk, const float* __restrict__ wv,
    const float* __restrict__ wo,
    unsigned short* __restrict__ xb, unsigned short* __restrict__ wqkvb,
    unsigned short* __restrict__ wob)
{
    const int z = blockIdx.y;
    const float* src; unsigned short* dst; int n4;
    if (z == 0)      { src = x;  dst = xb;                       n4 = (S * D) / 4; }
    else if (z == 1) { src = wq; dst = wqkvb;                    n4 = (D * D) / 4; }
    else if (z == 2) { src = wk; dst = wqkvb + (size_t)D * D;    n4 = (D * D) / 4; }
    else if (z == 3) { src = wv; dst = wqkvb + 2 * (size_t)D * D; n4 = (D * D) / 4; }
    else             { src = wo; dst = wob;                      n4 = (D * D) / 4; }
    int i = blockIdx.x * 256 + threadIdx.x;
    if (i < n4) {
        float4 v = ((const float4*)src)[i];
        ushort4 o;
        o.x = f2b(v.x); o.y = f2b(v.y); o.z = f2b(v.z); o.w = f2b(v.w);
        ((ushort4*)dst)[i] = o;
    }
}

// ---------------- bf16 NT GEMM: C = A @ B^T ------------------------------
// OUTMODE 0: bf16 out split by n>>11 into O0/O1/O2; Q (sel0) and K (sel1)
// get fused per-head RMSNorm (n-tile of 128 == one head); Q also gets the
// 1/sqrt(HD) score scale.  OUTMODE 1: fp32 out to O0.
template<int OUTMODE>
__global__ __launch_bounds__(256) void gemm_nt(
    const unsigned short* __restrict__ A, const unsigned short* __restrict__ B,
    void* __restrict__ O0, void* __restrict__ O1, void* __restrict__ O2,
    const float* __restrict__ qw, const float* __restrict__ kw)
{
    __shared__ short As[128 * 32];
    __shared__ short Bs[128 * 32];
    __shared__ float red[2][128];

    const int tid = threadIdx.x;
    const int m0 = blockIdx.y * 128, n0 = blockIdx.x * 128;
    const int w = tid >> 6, lane = tid & 63, col = lane & 15, quad = lane >> 4;
    const int mw = (w >> 1) * 64, nw = (w & 1) * 64;

    const int r0 = tid >> 2, k80 = (tid & 3) << 3;
    const size_t aoff = (size_t)(m0 + r0) * 2048 + k80;
    const size_t boff = (size_t)(n0 + r0) * 2048 + k80;

    f32x4 acc[4][4];
    #pragma unroll
    for (int i = 0; i < 4; ++i)
        #pragma unroll
        for (int j = 0; j < 4; ++j)
            #pragma unroll
            for (int r = 0; r < 4; ++r) acc[i][j][r] = 0.0f;

    for (int k0 = 0; k0 < 2048; k0 += 32) {
        gld16(&A[aoff + k0],               &As[tid * 8]);
        gld16(&A[aoff + 64 * 2048 + k0],   &As[(tid + 256) * 8]);
        gld16(&B[boff + k0],               &Bs[tid * 8]);
        gld16(&B[boff + 64 * 2048 + k0],   &Bs[(tid + 256) * 8]);
        __syncthreads();
        bf16x8 af[4], bf[4];
        #pragma unroll
        for (int i = 0; i < 4; ++i)
            af[i] = *(const bf16x8*)&As[(mw + 16 * i + col) * 32 + quad * 8];
        #pragma unroll
        for (int j = 0; j < 4; ++j)
            bf[j] = *(const bf16x8*)&Bs[(nw + 16 * j + col) * 32 + quad * 8];
        #pragma unroll
        for (int i = 0; i < 4; ++i)
            #pragma unroll
            for (int j = 0; j < 4; ++j)
                acc[i][j] = __builtin_amdgcn_mfma_f32_16x16x32_bf16(af[i], bf[j], acc[i][j], 0, 0, 0);
        __syncthreads();
    }

    if (OUTMODE == 1) {
        float* C = (float*)O0;
        #pragma unroll
        for (int i = 0; i < 4; ++i)
            #pragma unroll
            for (int j = 0; j < 4; ++j)
                #pragma unroll
                for (int r = 0; r < 4; ++r)
                    C[(size_t)(m0 + mw + 16 * i + quad * 4 + r) * 2048 + n0 + nw + 16 * j + col] = acc[i][j][r];
    } else {
        const int sel = n0 >> 11;
        unsigned short* C = (unsigned short*)(sel == 0 ? O0 : sel == 1 ? O1 : O2);
        const int nc0 = (n0 & 2047) + nw + col;
        float rsc[4][4];
        float wv[4] = {1.0f, 1.0f, 1.0f, 1.0f};
        if (sel <= 1) {
            // fused RMSNorm over the head (this block's 128 n-cols)
            const float* wgt = (sel == 0) ? qw : kw;
            const float extra = (sel == 0) ? 0.08838834764831845f : 1.0f;
            #pragma unroll
            for (int j = 0; j < 4; ++j) wv[j] = wgt[nw + 16 * j + col];
            #pragma unroll
            for (int i = 0; i < 4; ++i)
                #pragma unroll
                for (int r = 0; r < 4; ++r) {
                    float ss = 0.0f;
                    #pragma unroll
                    for (int j = 0; j < 4; ++j) ss += acc[i][j][r] * acc[i][j][r];
                    #pragma unroll
                    for (int d = 1; d < 16; d <<= 1) ss += __shfl_xor(ss, d, 64);
                    if (col == 0) red[w & 1][mw + 16 * i + quad * 4 + r] = ss;
                }
            __syncthreads();
            #pragma unroll
            for (int i = 0; i < 4; ++i)
                #pragma unroll
                for (int r = 0; r < 4; ++r) {
                    float tot = red[0][mw + 16 * i + quad * 4 + r] + red[1][mw + 16 * i + quad * 4 + r];
                    rsc[i][r] = rsqrtf(tot * (1.0f / HD) + 1e-6f) * extra;
                }
        } else {
            #pragma unroll
            for (int i = 0; i < 4; ++i)
                #pragma unroll
                for (int r = 0; r < 4; ++r) rsc[i][r] = 1.0f;
        }
        #pragma unroll
        for (int i = 0; i < 4; ++i)
            #pragma unroll
            for (int j = 0; j < 4; ++j)
                #pragma unroll
                for (int r = 0; r < 4; ++r)
                    C[(size_t)(m0 + mw + 16 * i + quad * 4 + r) * 2048 + nc0 + 16 * j] =
                        f2b(acc[i][j][r] * rsc[i][r] * wv[j]);
    }
}

// ---------------- V transpose: V[s][2048] -> Vt[h][dv][s] ----------------
__global__ __launch_bounds__(256) void transpose_v(
    const unsigned short* __restrict__ V, unsigned short* __restrict__ Vt)
{
    __shared__ short T[64][80];
    const int tid = threadIdx.x;
    const int c0 = blockIdx.x * 64, r0 = blockIdx.y * 64;

    #pragma unroll
    for (int it = 0; it < 2; ++it) {
        int idx = tid + (it << 8);
        int r = idx >> 3, c8 = (idx & 7) << 3;
        *(bf16x8*)&T[r][c8] = *(const bf16x8*)&V[(size_t)(r0 + r) * 2048 + c0 + c8];
    }
    __syncthreads();
    #pragma unroll
    for (int it = 0; it < 2; ++it) {
        int cc = tid & 63, sg = (tid >> 6) + (it << 2);
        int colg = c0 + cc;
        int h = colg >> 7, dv = colg & 127;
        short tmp[8];
        #pragma unroll
        for (int j = 0; j < 8; ++j) tmp[j] = T[sg * 8 + j][cc];
        *(bf16x8*)&Vt[(size_t)h * (HD * S) + (size_t)dv * S + r0 + sg * 8] = *(const bf16x8*)tmp;
    }
}

// ---------------- MFMA flash attention v3 --------------------------------
// BQ=128 (32 q-rows/wave), BK=64. K B-fragments loaded directly from global
// (L2/L3-resident); V double-buffered in LDS via global_load_lds; P round-
// trips through an XOR-swizzled LDS buffer. No-max softmax (|score|<=11.32).
__global__ __launch_bounds__(256, 2) void flash_mfma(
    const unsigned short* __restrict__ Qg, const unsigned short* __restrict__ Kg,
    const unsigned short* __restrict__ Vt, unsigned short* __restrict__ Ctx)
{
    __shared__ short Vs[2][2 * 128 * 32];   // [buf][ks][dv][32]
    __shared__ short Ps[128 * 64];          // XOR-swizzled, per-wave rows

    const int tid = threadIdx.x;
    const int w = tid >> 6, lane = tid & 63, col = lane & 15, quad = lane >> 4;
    const int q0 = blockIdx.x * 128, h = blockIdx.y;
    const size_t vbase = (size_t)h * (HD * S);

    // Q fragments in registers: 2 q-subtiles x 4 d-steps
    bf16x8 aq[2][4];
    #pragma unroll
    for (int qs = 0; qs < 2; ++qs) {
        const size_t qoff = (size_t)(q0 + w * 32 + qs * 16 + col) * 2048 + h * 128 + quad * 8;
        #pragma unroll
        for (int ds = 0; ds < 4; ++ds)
            aq[qs][ds] = *(const bf16x8*)&Qg[qoff + ds * 32];
    }

    float l_r[2][4] = {{0.f,0.f,0.f,0.f},{0.f,0.f,0.f,0.f}};
    f32x4 o[2][8];
    #pragma unroll
    for (int qs = 0; qs < 2; ++qs)
        #pragma unroll
        for (int nj = 0; nj < 8; ++nj)
            #pragma unroll
            for (int r = 0; r < 4; ++r) o[qs][nj][r] = 0.0f;

    auto stageV = [&](int j0s, int b) {
        #pragma unroll
        for (int it = 0; it < 4; ++it) {
            int c = tid + (it << 8);
            int ks = c >> 9, rem = c & 511, dv = rem >> 2, k8 = (rem & 3) << 3;
            gld16(&Vt[vbase + (size_t)dv * S + j0s + ks * 32 + k8], &Vs[b][c * 8]);
        }
    };

    auto compute = [&](int b, int jt) {
        // ---- QK^T: K B-frags straight from global ----
        f32x4 sc[2][4];
        #pragma unroll
        for (int qs = 0; qs < 2; ++qs)
            #pragma unroll
            for (int kj = 0; kj < 4; ++kj)
                #pragma unroll
                for (int r = 0; r < 4; ++r) sc[qs][kj][r] = 0.0f;
        const size_t kbase = (size_t)(jt + col) * 2048 + h * 128 + quad * 8;
        #pragma unroll
        for (int ds = 0; ds < 4; ++ds)
            #pragma unroll
            for (int kj = 0; kj < 4; ++kj) {
                bf16x8 bk = *(const bf16x8*)&Kg[kbase + (size_t)kj * 16 * 2048 + ds * 32];
                sc[0][kj] = __builtin_amdgcn_mfma_f32_16x16x32_bf16(aq[0][ds], bk, sc[0][kj], 0, 0, 0);
                sc[1][kj] = __builtin_amdgcn_mfma_f32_16x16x32_bf16(aq[1][ds], bk, sc[1][kj], 0, 0, 0);
            }

        // ---- exp, write P to swizzled LDS (wave-private rows) ----
        #pragma unroll
        for (int qs = 0; qs < 2; ++qs)
            #pragma unroll
            for (int kj = 0; kj < 4; ++kj)
                #pragma unroll
                for (int r = 0; r < 4; ++r) {
                    unsigned short pb = f2b(__expf(sc[qs][kj][r]));
                    int ql = w * 32 + qs * 16 + quad * 4 + r;
                    int kk = kj * 16 + col;
                    Ps[ql * 64 + (kk ^ ((ql & 7) << 3))] = (short)pb;
                    l_r[qs][r] += b2f(pb);
                }

        // ---- O += P @ V ----
        #pragma unroll
        for (int ks = 0; ks < 2; ++ks) {
            bf16x8 ap[2];
            #pragma unroll
            for (int qs = 0; qs < 2; ++qs) {
                int qrow = w * 32 + qs * 16 + col;
                int k0 = ks * 32 + quad * 8;
                ap[qs] = *(const bf16x8*)&Ps[qrow * 64 + (k0 ^ ((qrow & 7) << 3))];
            }
            #pragma unroll
            for (int nj = 0; nj < 8; ++nj) {
                bf16x8 bv = *(const bf16x8*)&Vs[b][(ks * 128 + nj * 16 + col) * 32 + quad * 8];
                o[0][nj] = __builtin_amdgcn_mfma_f32_16x16x32_bf16(ap[0], bv, o[0][nj], 0, 0, 0);
                o[1][nj] = __builtin_amdgcn_mfma_f32_16x16x32_bf16(ap[1], bv, o[1][nj], 0, 0, 0);
            }
        }
    };

    stageV(0, 0);
    for (int j0 = 0; j0 < S; j0 += 128) {
        __syncthreads();                        // buf0 ready; buf1 free
        stageV(j0 + 64, 1);                     // prefetch (async DMA)
        compute(0, j0);
        __syncthreads();                        // buf1 ready; buf0 free
        if (j0 + 128 < S) stageV(j0 + 128, 0);
        compute(1, j0 + 64);
    }

    // reduce l across the 16 col-lanes, write O/l
    #pragma unroll
    for (int d = 1; d < 16; d <<= 1)
        #pragma unroll
        for (int qs = 0; qs < 2; ++qs)
            #pragma unroll
            for (int r = 0; r < 4; ++r) l_r[qs][r] += __shfl_xor(l_r[qs][r], d, 64);

    #pragma unroll
    for (int qs = 0; qs < 2; ++qs) {
        float inv[4];
        #pragma unroll
        for (int r = 0; r < 4; ++r) inv[r] = 1.0f / l_r[qs][r];
        #pragma unroll
        for (int nj = 0; nj < 8; ++nj)
            #pragma unroll
            for (int r = 0; r < 4; ++r)
                Ctx[(size_t)(q0 + w * 32 + qs * 16 + quad * 4 + r) * 2048 + h * 128 + nj * 16 + col] =
                    f2b(o[qs][nj][r] * inv[r]);
    }
}

extern "C" void kernel_launch(void* const* d_in, const int* in_sizes, int n_in,
                              void* d_out, int out_size, void* d_ws, size_t ws_size,
                              hipStream_t stream)
{
    const float* x  = (const float*)d_in[0];
    const float* wq = (const float*)d_in[1];
    const float* wk = (const float*)d_in[2];
    const float* wv = (const float*)d_in[3];
    const float* wo = (const float*)d_in[4];
    const float* qw = (const float*)d_in[5];
    const float* kw = (const float*)d_in[6];
    float* out = (float*)d_out;

    const size_t MB = 1u << 20;
    char* ws = (char*)d_ws;
    unsigned short* xb    = (unsigned short*)(ws);             // 16 MB; later Ctx
    unsigned short* Wqkvb = (unsigned short*)(ws + 16 * MB);   // 24 MB; later Vt
    unsigned short* Wob   = (unsigned short*)(ws + 40 * MB);   //  8 MB
    unsigned short* Qb    = (unsigned short*)(ws + 48 * MB);   // 16 MB
    unsigned short* Kb    = (unsigned short*)(ws + 64 * MB);   // 16 MB
    unsigned short* Vb    = (unsigned short*)(ws + 80 * MB);   // 16 MB
    unsigned short* Vt    = Wqkvb;                             // overlay after proj
    unsigned short* Ctx   = xb;                                // overlay after proj

    cvt_all<<<dim3(8192, 5), dim3(256), 0, stream>>>(x, wq, wk, wv, wo, xb, Wqkvb, Wob);

    // fused QKV projection + RMSNorm epilogue
    gemm_nt<0><<<dim3(48, 32), dim3(256), 0, stream>>>(xb, Wqkvb, Qb, Kb, Vb, qw, kw);

    transpose_v<<<dim3(32, 64), dim3(256), 0, stream>>>(Vb, Vt);

    flash_mfma<<<dim3(32, 16), dim3(256), 0, stream>>>(Qb, Kb, Vt, Ctx);

    gemm_nt<1><<<dim3(16, 32), dim3(256), 0, stream>>>(Ctx, Wob, out, out, out, qw, kw);
}

// Round 5
// 506.304 us; speedup vs baseline: 1.2770x; 1.2770x over previous
//
#include <hip/hip_runtime.h>
#include <hip/hip_bf16.h>

#define S 4096
#define D 2048
#define NH 16
#define HD 128

typedef __attribute__((ext_vector_type(8))) short bf16x8;
typedef __attribute__((ext_vector_type(4))) float f32x4;

typedef __attribute__((address_space(1))) char glob_char;
typedef __attribute__((address_space(3))) char lds_char_t;

__device__ __forceinline__ void gld16(const void* g, void* l) {
    __builtin_amdgcn_global_load_lds((const glob_char*)g, (lds_char_t*)l, 16, 0, 0);
}

__device__ __forceinline__ unsigned short f2b(float f) {
    union { float f; unsigned u; } c; c.f = f;
    unsigned r = c.u + 0x7fff + ((c.u >> 16) & 1);
    return (unsigned short)(r >> 16);
}
__device__ __forceinline__ float b2f(unsigned short u) {
    union { unsigned u; float f; } c; c.u = ((unsigned)u) << 16;
    return c.f;
}

// ---------------- fp32 -> bf16 conversion (all 5 tensors, one launch) ----
__global__ __launch_bounds__(256) void cvt_all(
    const float* __restrict__ x,  const float* __restrict__ wq,
    const float* __restrict__ wk, const float* __restrict__ wv,
    const float* __restrict__ wo,
    unsigned short* __restrict__ xb, unsigned short* __restrict__ wqkvb,
    unsigned short* __restrict__ wob)
{
    const int z = blockIdx.y;
    const float* src; unsigned short* dst; int n4;
    if (z == 0)      { src = x;  dst = xb;                        n4 = (S * D) / 4; }
    else if (z == 1) { src = wq; dst = wqkvb;                     n4 = (D * D) / 4; }
    else if (z == 2) { src = wk; dst = wqkvb + (size_t)D * D;     n4 = (D * D) / 4; }
    else if (z == 3) { src = wv; dst = wqkvb + 2 * (size_t)D * D; n4 = (D * D) / 4; }
    else             { src = wo; dst = wob;                       n4 = (D * D) / 4; }
    int i = blockIdx.x * 256 + threadIdx.x;
    if (i < n4) {
        float4 v = ((const float4*)src)[i];
        ushort4 o;
        o.x = f2b(v.x); o.y = f2b(v.y); o.z = f2b(v.z); o.w = f2b(v.w);
        ((ushort4*)dst)[i] = o;
    }
}

// ---------------- bf16 NT GEMM: C = A @ B^T ------------------------------
// OUTMODE 0: n<2048 -> Q (O0, fused RMSNorm + 1/sqrt(HD)); n in [2048,4096)
// -> K (O1, fused RMSNorm); n >= 4096 -> V written TRANSPOSED to O2 as
// Vt[h][dv][s].  OUTMODE 1: fp32 out to O0.
template<int OUTMODE>
__global__ __launch_bounds__(256) void gemm_nt(
    const unsigned short* __restrict__ A, const unsigned short* __restrict__ B,
    void* __restrict__ O0, void* __restrict__ O1, void* __restrict__ O2,
    const float* __restrict__ qw, const float* __restrict__ kw)
{
    __shared__ short As[128 * 32];
    __shared__ short Bs[128 * 32];
    __shared__ float red[2][128];

    const int tid = threadIdx.x;
    const int m0 = blockIdx.y * 128, n0 = blockIdx.x * 128;
    const int w = tid >> 6, lane = tid & 63, col = lane & 15, quad = lane >> 4;
    const int mw = (w >> 1) * 64, nw = (w & 1) * 64;

    const int r0 = tid >> 2, k80 = (tid & 3) << 3;
    const size_t aoff = (size_t)(m0 + r0) * 2048 + k80;
    const size_t boff = (size_t)(n0 + r0) * 2048 + k80;

    f32x4 acc[4][4];
    #pragma unroll
    for (int i = 0; i < 4; ++i)
        #pragma unroll
        for (int j = 0; j < 4; ++j)
            #pragma unroll
            for (int r = 0; r < 4; ++r) acc[i][j][r] = 0.0f;

    for (int k0 = 0; k0 < 2048; k0 += 32) {
        gld16(&A[aoff + k0],               &As[tid * 8]);
        gld16(&A[aoff + 64 * 2048 + k0],   &As[(tid + 256) * 8]);
        gld16(&B[boff + k0],               &Bs[tid * 8]);
        gld16(&B[boff + 64 * 2048 + k0],   &Bs[(tid + 256) * 8]);
        __syncthreads();
        bf16x8 af[4], bf[4];
        #pragma unroll
        for (int i = 0; i < 4; ++i)
            af[i] = *(const bf16x8*)&As[(mw + 16 * i + col) * 32 + quad * 8];
        #pragma unroll
        for (int j = 0; j < 4; ++j)
            bf[j] = *(const bf16x8*)&Bs[(nw + 16 * j + col) * 32 + quad * 8];
        #pragma unroll
        for (int i = 0; i < 4; ++i)
            #pragma unroll
            for (int j = 0; j < 4; ++j)
                acc[i][j] = __builtin_amdgcn_mfma_f32_16x16x32_bf16(af[i], bf[j], acc[i][j], 0, 0, 0);
        __syncthreads();
    }

    if (OUTMODE == 1) {
        float* C = (float*)O0;
        #pragma unroll
        for (int i = 0; i < 4; ++i)
            #pragma unroll
            for (int j = 0; j < 4; ++j)
                #pragma unroll
                for (int r = 0; r < 4; ++r)
                    C[(size_t)(m0 + mw + 16 * i + quad * 4 + r) * 2048 + n0 + nw + 16 * j + col] = acc[i][j][r];
    } else {
        const int sel = n0 >> 11;
        if (sel == 2) {
            // V: write transposed -> Vt[h][dv][s], 4 consecutive s per lane
            unsigned short* VtO = (unsigned short*)O2;
            #pragma unroll
            for (int i = 0; i < 4; ++i)
                #pragma unroll
                for (int j = 0; j < 4; ++j) {
                    int n = (n0 & 2047) + nw + 16 * j + col;
                    int hh = n >> 7, dv = n & 127;
                    ushort4 pk;
                    pk.x = f2b(acc[i][j][0]); pk.y = f2b(acc[i][j][1]);
                    pk.z = f2b(acc[i][j][2]); pk.w = f2b(acc[i][j][3]);
                    *(ushort4*)&VtO[(size_t)hh * (HD * S) + (size_t)dv * S +
                                    m0 + mw + 16 * i + quad * 4] = pk;
                }
        } else {
            unsigned short* C = (unsigned short*)(sel == 0 ? O0 : O1);
            const int nc0 = (n0 & 2047) + nw + col;
            const float* wgt = (sel == 0) ? qw : kw;
            const float extra = (sel == 0) ? 0.08838834764831845f : 1.0f;
            float wv[4];
            #pragma unroll
            for (int j = 0; j < 4; ++j) wv[j] = wgt[nw + 16 * j + col];
            float rsc[4][4];
            #pragma unroll
            for (int i = 0; i < 4; ++i)
                #pragma unroll
                for (int r = 0; r < 4; ++r) {
                    float ss = 0.0f;
                    #pragma unroll
                    for (int j = 0; j < 4; ++j) ss += acc[i][j][r] * acc[i][j][r];
                    #pragma unroll
                    for (int d = 1; d < 16; d <<= 1) ss += __shfl_xor(ss, d, 64);
                    if (col == 0) red[w & 1][mw + 16 * i + quad * 4 + r] = ss;
                }
            __syncthreads();
            #pragma unroll
            for (int i = 0; i < 4; ++i)
                #pragma unroll
                for (int r = 0; r < 4; ++r) {
                    float tot = red[0][mw + 16 * i + quad * 4 + r] + red[1][mw + 16 * i + quad * 4 + r];
                    rsc[i][r] = rsqrtf(tot * (1.0f / HD) + 1e-6f) * extra;
                }
            #pragma unroll
            for (int i = 0; i < 4; ++i)
                #pragma unroll
                for (int j = 0; j < 4; ++j)
                    #pragma unroll
                    for (int r = 0; r < 4; ++r)
                        C[(size_t)(m0 + mw + 16 * i + quad * 4 + r) * 2048 + nc0 + 16 * j] =
                            f2b(acc[i][j][r] * rsc[i][r] * wv[j]);
        }
    }
}

// ---------------- MFMA flash attention v4 --------------------------------
// BQ=128 (32 q-rows/wave), BK=64. K and V staged in LDS via global_load_lds,
// double-buffered (1 barrier per tile). Chunk-XOR swizzle on K/V layouts
// makes fragment ds_read_b128 2-way (free). No-max softmax (|score|<=11.32).
__global__ __launch_bounds__(256, 2) void flash_mfma(
    const unsigned short* __restrict__ Qg, const unsigned short* __restrict__ Kg,
    const unsigned short* __restrict__ Vt, unsigned short* __restrict__ Ctx)
{
    __shared__ short Ks[2][4 * 64 * 32];    // [buf][ds][key][4 chunks of 8]
    __shared__ short Vs[2][2 * 128 * 32];   // [buf][ks][dv][4 chunks of 8]
    __shared__ short Ps[128 * 64];          // XOR-swizzled, wave-private rows

    const int tid = threadIdx.x;
    const int w = tid >> 6, lane = tid & 63, col = lane & 15, quad = lane >> 4;
    const int q0 = blockIdx.x * 128, h = blockIdx.y;
    const size_t vbase = (size_t)h * (HD * S);

    // Q fragments in registers: 2 q-subtiles x 4 d-steps
    bf16x8 aq[2][4];
    #pragma unroll
    for (int qs = 0; qs < 2; ++qs) {
        const size_t qoff = (size_t)(q0 + w * 32 + qs * 16 + col) * 2048 + h * 128 + quad * 8;
        #pragma unroll
        for (int ds = 0; ds < 4; ++ds)
            aq[qs][ds] = *(const bf16x8*)&Qg[qoff + ds * 32];
    }

    float l_r[2][4] = {{0.f,0.f,0.f,0.f},{0.f,0.f,0.f,0.f}};
    f32x4 o[2][8];
    #pragma unroll
    for (int qs = 0; qs < 2; ++qs)
        #pragma unroll
        for (int nj = 0; nj < 8; ++nj)
            #pragma unroll
            for (int r = 0; r < 4; ++r) o[qs][nj][r] = 0.0f;

    auto stage = [&](int j0s, int b) {
        #pragma unroll
        for (int it = 0; it < 4; ++it) {
            int c = tid + (it << 8);
            int ds = c >> 8, rem = c & 255, key = rem >> 2, ch = rem & 3;
            int g = ch ^ ((key >> 1) & 3);          // chunk swizzle
            gld16(&Kg[(size_t)(j0s + key) * 2048 + h * 128 + ds * 32 + g * 8], &Ks[b][c * 8]);
        }
        #pragma unroll
        for (int it = 0; it < 4; ++it) {
            int c = tid + (it << 8);
            int ks = c >> 9, rem = c & 511, dv = rem >> 2, ch = rem & 3;
            int g = ch ^ ((dv >> 1) & 3);           // chunk swizzle
            gld16(&Vt[vbase + (size_t)dv * S + j0s + ks * 32 + g * 8], &Vs[b][c * 8]);
        }
    };

    auto compute = [&](int b) {
        // ---- QK^T ----
        f32x4 sc[2][4];
        #pragma unroll
        for (int qs = 0; qs < 2; ++qs)
            #pragma unroll
            for (int kj = 0; kj < 4; ++kj)
                #pragma unroll
                for (int r = 0; r < 4; ++r) sc[qs][kj][r] = 0.0f;
        #pragma unroll
        for (int ds = 0; ds < 4; ++ds)
            #pragma unroll
            for (int kj = 0; kj < 4; ++kj) {
                int key = kj * 16 + col;
                bf16x8 bk = *(const bf16x8*)&Ks[b][(ds * 64 + key) * 32 +
                                                  ((quad ^ ((key >> 1) & 3)) << 3)];
                sc[0][kj] = __builtin_amdgcn_mfma_f32_16x16x32_bf16(aq[0][ds], bk, sc[0][kj], 0, 0, 0);
                sc[1][kj] = __builtin_amdgcn_mfma_f32_16x16x32_bf16(aq[1][ds], bk, sc[1][kj], 0, 0, 0);
            }

        // ---- exp, write P to swizzled LDS (wave-private rows) ----
        #pragma unroll
        for (int qs = 0; qs < 2; ++qs)
            #pragma unroll
            for (int kj = 0; kj < 4; ++kj)
                #pragma unroll
                for (int r = 0; r < 4; ++r) {
                    unsigned short pb = f2b(__expf(sc[qs][kj][r]));
                    int ql = w * 32 + qs * 16 + quad * 4 + r;
                    int kk = kj * 16 + col;
                    Ps[ql * 64 + (kk ^ ((ql & 7) << 3))] = (short)pb;
                    l_r[qs][r] += b2f(pb);
                }

        // ---- O += P @ V ----
        #pragma unroll
        for (int ks = 0; ks < 2; ++ks) {
            bf16x8 ap[2];
            #pragma unroll
            for (int qs = 0; qs < 2; ++qs) {
                int qrow = w * 32 + qs * 16 + col;
                int k0 = ks * 32 + quad * 8;
                ap[qs] = *(const bf16x8*)&Ps[qrow * 64 + (k0 ^ ((qrow & 7) << 3))];
            }
            #pragma unroll
            for (int nj = 0; nj < 8; ++nj) {
                int dv = nj * 16 + col;
                bf16x8 bv = *(const bf16x8*)&Vs[b][(ks * 128 + dv) * 32 +
                                                  ((quad ^ ((dv >> 1) & 3)) << 3)];
                o[0][nj] = __builtin_amdgcn_mfma_f32_16x16x32_bf16(ap[0], bv, o[0][nj], 0, 0, 0);
                o[1][nj] = __builtin_amdgcn_mfma_f32_16x16x32_bf16(ap[1], bv, o[1][nj], 0, 0, 0);
            }
        }
    };

    stage(0, 0);
    for (int j0 = 0; j0 < S; j0 += 128) {
        __syncthreads();                        // buf0 ready; buf1 free
        stage(j0 + 64, 1);                      // async prefetch
        compute(0);
        __syncthreads();                        // buf1 ready; buf0 free
        if (j0 + 128 < S) stage(j0 + 128, 0);
        compute(1);
    }

    // reduce l across the 16 col-lanes, write O/l
    #pragma unroll
    for (int d = 1; d < 16; d <<= 1)
        #pragma unroll
        for (int qs = 0; qs < 2; ++qs)
            #pragma unroll
            for (int r = 0; r < 4; ++r) l_r[qs][r] += __shfl_xor(l_r[qs][r], d, 64);

    #pragma unroll
    for (int qs = 0; qs < 2; ++qs) {
        float inv[4];
        #pragma unroll
        for (int r = 0; r < 4; ++r) inv[r] = 1.0f / l_r[qs][r];
        #pragma unroll
        for (int nj = 0; nj < 8; ++nj)
            #pragma unroll
            for (int r = 0; r < 4; ++r)
                Ctx[(size_t)(q0 + w * 32 + qs * 16 + quad * 4 + r) * 2048 + h * 128 + nj * 16 + col] =
                    f2b(o[qs][nj][r] * inv[r]);
    }
}

extern "C" void kernel_launch(void* const* d_in, const int* in_sizes, int n_in,
                              void* d_out, int out_size, void* d_ws, size_t ws_size,
                              hipStream_t stream)
{
    const float* x  = (const float*)d_in[0];
    const float* wq = (const float*)d_in[1];
    const float* wk = (const float*)d_in[2];
    const float* wv = (const float*)d_in[3];
    const float* wo = (const float*)d_in[4];
    const float* qw = (const float*)d_in[5];
    const float* kw = (const float*)d_in[6];
    float* out = (float*)d_out;

    const size_t MB = 1u << 20;
    char* ws = (char*)d_ws;
    unsigned short* xb    = (unsigned short*)(ws);             // 16 MB; later Ctx
    unsigned short* Wqkvb = (unsigned short*)(ws + 16 * MB);   // 24 MB
    unsigned short* Wob   = (unsigned short*)(ws + 40 * MB);   //  8 MB
    unsigned short* Qb    = (unsigned short*)(ws + 48 * MB);   // 16 MB
    unsigned short* Kb    = (unsigned short*)(ws + 64 * MB);   // 16 MB
    unsigned short* Vt    = (unsigned short*)(ws + 80 * MB);   // 16 MB [h][dv][s]
    unsigned short* Ctx   = xb;                                // overlay after proj

    cvt_all<<<dim3(8192, 5), dim3(256), 0, stream>>>(x, wq, wk, wv, wo, xb, Wqkvb, Wob);

    // fused QKV projection + RMSNorm epilogue + transposed V write
    gemm_nt<0><<<dim3(48, 32), dim3(256), 0, stream>>>(xb, Wqkvb, Qb, Kb, Vt, qw, kw);

    flash_mfma<<<dim3(32, 16), dim3(256), 0, stream>>>(Qb, Kb, Vt, Ctx);

    gemm_nt<1><<<dim3(16, 32), dim3(256), 0, stream>>>(Ctx, Wob, out, out, out, qw, kw);
}